// Round 4
// baseline (261.544 us; speedup 1.0000x reference)
//
#include <hip/hip_runtime.h>
#include <math.h>

#define U_DIM 400
#define V_DIM 400
#define TEXELS (U_DIM * V_DIM)
#define VHALF (V_DIM / 2)

// clang native vector types (HIP float2/int2 are classes and are rejected by
// __builtin_nontemporal_load; ext_vector_type is accepted).
typedef float vfloat2 __attribute__((ext_vector_type(2)));
typedef int   vint2   __attribute__((ext_vector_type(2)));

// ---------------- q10 packed path, 2x2 tiled ----------------
// Per-texel record: 16 B = 128 bits:
//   bits [10k, 10k+10) for k=0..11 : q_k = round(v_k * 2^(9-e)) + 512  (10-bit)
//   bits [120,128)                 : Eb = e + 127 (biased exponent of max|v|)
// Dequant: v_k = (q_k - 512) * 2^(e-9) (power-of-2 scale, exact in fp32).
//
// Layout: records stored in 2x2 texel blocks, 64 B aligned:
//   R(i,j) = ((i>>1)*VHALF + (j>>1))*4 + (i&1)*2 + (j&1)
// A bilinear query's 4 corners span on average 2.25 blocks x 64 B = 144 B of
// cache footprint (vs ~2.25 x 128 B lines across distant rows in row-major);
// with even i1,j1 (25% of points) ALL 4 corners are one 64 B block.

__device__ __forceinline__ unsigned morton_idx(int i, int j) {
  return (unsigned)(((i >> 1) * VHALF + (j >> 1)) << 2) + ((i & 1) << 1) + (j & 1);
}

__global__ __launch_bounds__(256) void repack_q10m_kernel(
    const float* __restrict__ mp, const float* __restrict__ bp,
    uint4* __restrict__ packed, int total_texels) {
  int t = blockIdx.x * blockDim.x + threadIdx.x;
  if (t >= total_texels) return;
  float vals[12];
  const float* pm = mp + (size_t)t * 9;
  const float* pb = bp + (size_t)t * 3;
#pragma unroll
  for (int k = 0; k < 9; ++k) vals[k] = __builtin_nontemporal_load(pm + k);
#pragma unroll
  for (int k = 0; k < 3; ++k) vals[9 + k] = __builtin_nontemporal_load(pb + k);

  float mx = 0.0f;
#pragma unroll
  for (int k = 0; k < 12; ++k) mx = fmaxf(mx, fabsf(vals[k]));
  int e;
  (void)frexpf(mx, &e);  // mx = f * 2^e, f in [0.5,1); mx==0 -> e=0
  int Eb = e + 127;
  if (Eb < 10) Eb = 10;
  if (Eb > 255) Eb = 255;
  float inv = __uint_as_float((unsigned)((9 - (Eb - 127) + 127) << 23));  // 2^(9-e)

  unsigned d[4] = {0u, 0u, 0u, 0u};
#pragma unroll
  for (int k = 0; k < 12; ++k) {
    float qf = rintf(vals[k] * inv);
    qf = fminf(fmaxf(qf, -512.0f), 511.0f);
    unsigned q = (unsigned)((int)qf + 512);
    int bit = 10 * k;
    d[bit >> 5] |= q << (bit & 31);
    if ((bit & 31) + 10 > 32) d[(bit >> 5) + 1] |= q >> (32 - (bit & 31));
  }
  d[3] |= (unsigned)Eb << 24;

  int mi = t / TEXELS;
  int r  = t - mi * TEXELS;
  int i  = r / V_DIM;
  int j  = r - i * V_DIM;
  unsigned R = (unsigned)mi * (unsigned)TEXELS + morton_idx(i, j);
  packed[R] = make_uint4(d[0], d[1], d[2], d[3]);
}

__device__ __forceinline__ void accum_q10(uint4 r, float wc, float* acc,
                                          float& wsum) {
  unsigned d0 = r.x, d1 = r.y, d2 = r.z, d3 = r.w;
  float s = __uint_as_float(((d3 >> 24) - 9u) << 23);  // 2^(e-9), exact
  float ws = wc * s;
  wsum += ws;
  unsigned q[12];
  q[0]  = d0 & 1023u;
  q[1]  = (d0 >> 10) & 1023u;
  q[2]  = (d0 >> 20) & 1023u;
  q[3]  = ((d0 >> 30) | (d1 << 2)) & 1023u;
  q[4]  = (d1 >> 8) & 1023u;
  q[5]  = (d1 >> 18) & 1023u;
  q[6]  = ((d1 >> 28) | (d2 << 4)) & 1023u;
  q[7]  = (d2 >> 6) & 1023u;
  q[8]  = (d2 >> 16) & 1023u;
  q[9]  = ((d2 >> 26) | (d3 << 6)) & 1023u;
  q[10] = (d3 >> 4) & 1023u;
  q[11] = (d3 >> 14) & 1023u;
#pragma unroll
  for (int k = 0; k < 12; ++k)
    acc[k] = fmaf(ws, (float)q[k], acc[k]);
}

struct Corners {
  unsigned t00, t10, t01, t11;
  float w00, w10, w01, w11;
};

__device__ __forceinline__ Corners make_corners(float un, float vn) {
  float iu = un * (float)U_DIM; if (iu >= (float)U_DIM) iu = (float)(U_DIM - 1);
  float jv = vn * (float)V_DIM; if (jv >= (float)V_DIM) jv = (float)(V_DIM - 1);
  float i1f = floorf(iu), j1f = floorf(jv);
  int i1 = (int)i1f, j1 = (int)j1f;
  int i2 = i1 + 1; if (i2 == U_DIM) i2 = 0;
  int j2 = j1 + 1; if (j2 == V_DIM) j2 = 0;
  float ir = iu - i1f, jr = jv - j1f;
  Corners c;
  c.w00 = (1.0f - ir) * (1.0f - jr);
  c.w10 = ir * (1.0f - jr);
  c.w01 = (1.0f - ir) * jr;
  c.w11 = ir * jr;
  c.t00 = morton_idx(i1, j1);
  c.t10 = morton_idx(i2, j1);
  c.t01 = morton_idx(i1, j2);
  c.t11 = morton_idx(i2, j2);
  return c;
}

__device__ __forceinline__ void finish_point(
    const float* acc, float wsum, float x0, float x1, float x2,
    float* __restrict__ out, size_t n) {
  float cc = (512.0f * wsum) * (x0 + x1 + x2 + 1.0f);
  float o0 = fmaf(x0, acc[0], fmaf(x1, acc[3], fmaf(x2, acc[6], acc[9])))  - cc;
  float o1 = fmaf(x0, acc[1], fmaf(x1, acc[4], fmaf(x2, acc[7], acc[10]))) - cc;
  float o2 = fmaf(x0, acc[2], fmaf(x1, acc[5], fmaf(x2, acc[8], acc[11]))) - cc;
  __builtin_nontemporal_store(o0, out + 3 * n + 0);
  __builtin_nontemporal_store(o1, out + 3 * n + 1);
  __builtin_nontemporal_store(o2, out + 3 * n + 2);
}

// Two points per thread: 8 gather loads in flight, vectorized stream loads.
__global__ __launch_bounds__(256) void interp_q10m_kernel(
    const float* __restrict__ x, const int* __restrict__ mat,
    const float* __restrict__ u, const float* __restrict__ v,
    const uint4* __restrict__ packed, float* __restrict__ out, int N) {
  int t = blockIdx.x * blockDim.x + threadIdx.x;
  size_t nA = (size_t)t * 2;
  if (nA >= (size_t)N) return;
  bool has2 = (nA + 1) < (size_t)N;

  if (has2) {
    vfloat2 uu  = __builtin_nontemporal_load((const vfloat2*)(u) + t);
    vfloat2 vv  = __builtin_nontemporal_load((const vfloat2*)(v) + t);
    vint2   mm  = __builtin_nontemporal_load((const vint2*)(mat) + t);
    vfloat2 xf0 = __builtin_nontemporal_load((const vfloat2*)(x) + 3 * t + 0);
    vfloat2 xf1 = __builtin_nontemporal_load((const vfloat2*)(x) + 3 * t + 1);
    vfloat2 xf2 = __builtin_nontemporal_load((const vfloat2*)(x) + 3 * t + 2);

    Corners cA = make_corners(uu.x, vv.x);
    Corners cB = make_corners(uu.y, vv.y);
    const uint4* baseA = packed + (size_t)mm.x * (size_t)TEXELS;
    const uint4* baseB = packed + (size_t)mm.y * (size_t)TEXELS;

    // Issue all 8 gathers before consuming any.
    uint4 rA00 = baseA[cA.t00];
    uint4 rA10 = baseA[cA.t10];
    uint4 rA01 = baseA[cA.t01];
    uint4 rA11 = baseA[cA.t11];
    uint4 rB00 = baseB[cB.t00];
    uint4 rB10 = baseB[cB.t10];
    uint4 rB01 = baseB[cB.t01];
    uint4 rB11 = baseB[cB.t11];

    float accA[12], accB[12];
#pragma unroll
    for (int c = 0; c < 12; ++c) { accA[c] = 0.0f; accB[c] = 0.0f; }
    float wsA = 0.0f, wsB = 0.0f;

    accum_q10(rA00, cA.w00, accA, wsA);
    accum_q10(rA10, cA.w10, accA, wsA);
    accum_q10(rA01, cA.w01, accA, wsA);
    accum_q10(rA11, cA.w11, accA, wsA);
    finish_point(accA, wsA, xf0.x, xf0.y, xf1.x, out, nA);

    accum_q10(rB00, cB.w00, accB, wsB);
    accum_q10(rB10, cB.w10, accB, wsB);
    accum_q10(rB01, cB.w01, accB, wsB);
    accum_q10(rB11, cB.w11, accB, wsB);
    finish_point(accB, wsB, xf1.y, xf2.x, xf2.y, out, nA + 1);
  } else {
    // tail: single point
    float un = __builtin_nontemporal_load(u + nA);
    float vn = __builtin_nontemporal_load(v + nA);
    int   mn = __builtin_nontemporal_load(mat + nA);
    float x0 = __builtin_nontemporal_load(x + 3 * nA + 0);
    float x1 = __builtin_nontemporal_load(x + 3 * nA + 1);
    float x2 = __builtin_nontemporal_load(x + 3 * nA + 2);
    Corners c = make_corners(un, vn);
    const uint4* base = packed + (size_t)mn * (size_t)TEXELS;
    uint4 r00 = base[c.t00];
    uint4 r10 = base[c.t10];
    uint4 r01 = base[c.t01];
    uint4 r11 = base[c.t11];
    float acc[12];
#pragma unroll
    for (int k = 0; k < 12; ++k) acc[k] = 0.0f;
    float ws = 0.0f;
    accum_q10(r00, c.w00, acc, ws);
    accum_q10(r10, c.w10, acc, ws);
    accum_q10(r01, c.w01, acc, ws);
    accum_q10(r11, c.w11, acc, ws);
    finish_point(acc, ws, x0, x1, x2, out, nA);
  }
}

// ---------------- fp32 direct fallback (ws too small) ----------------
__global__ __launch_bounds__(256) void interp_direct_kernel(
    const float* __restrict__ x, const int* __restrict__ mat,
    const float* __restrict__ u, const float* __restrict__ v,
    const float* __restrict__ mp, const float* __restrict__ bp,
    float* __restrict__ out, int N) {
  int n = blockIdx.x * blockDim.x + threadIdx.x;
  if (n >= N) return;

  float iu = u[n] * (float)U_DIM; if (iu >= (float)U_DIM) iu = (float)(U_DIM - 1);
  float jv = v[n] * (float)V_DIM; if (jv >= (float)V_DIM) jv = (float)(V_DIM - 1);
  float i1f = floorf(iu), j1f = floorf(jv);
  int i1 = (int)i1f, j1 = (int)j1f;
  int i2 = i1 + 1; if (i2 == U_DIM) i2 = 0;
  int j2 = j1 + 1; if (j2 == V_DIM) j2 = 0;
  float ir = iu - i1f, jr = jv - j1f;

  float w[4];
  w[0] = (1.0f - ir) * (1.0f - jr);
  w[1] = ir * (1.0f - jr);
  w[2] = (1.0f - ir) * jr;
  w[3] = ir * jr;
  int t[4];
  t[0] = i1 * V_DIM + j1;
  t[1] = i2 * V_DIM + j1;
  t[2] = i1 * V_DIM + j2;
  t[3] = i2 * V_DIM + j2;

  size_t mb = (size_t)mat[n] * TEXELS;
  float acc[12];
#pragma unroll
  for (int c = 0; c < 12; ++c) acc[c] = 0.0f;
#pragma unroll
  for (int c = 0; c < 4; ++c) {
    const float* pm = mp + (mb + t[c]) * 9;
    const float* pb = bp + (mb + t[c]) * 3;
    float wc = w[c];
#pragma unroll
    for (int k = 0; k < 9; ++k) acc[k] = fmaf(wc, pm[k], acc[k]);
#pragma unroll
    for (int k = 0; k < 3; ++k) acc[9 + k] = fmaf(wc, pb[k], acc[9 + k]);
  }

  float x0 = x[3 * n + 0];
  float x1 = x[3 * n + 1];
  float x2 = x[3 * n + 2];
  float o0 = fmaf(x0, acc[0], fmaf(x1, acc[3], fmaf(x2, acc[6], acc[9])));
  float o1 = fmaf(x0, acc[1], fmaf(x1, acc[4], fmaf(x2, acc[7], acc[10])));
  float o2 = fmaf(x0, acc[2], fmaf(x1, acc[5], fmaf(x2, acc[8], acc[11])));
  out[3 * n + 0] = o0;
  out[3 * n + 1] = o1;
  out[3 * n + 2] = o2;
}

extern "C" void kernel_launch(void* const* d_in, const int* in_sizes, int n_in,
                              void* d_out, int out_size, void* d_ws, size_t ws_size,
                              hipStream_t stream) {
  const float* x  = (const float*)d_in[0];
  const int*   m  = (const int*)d_in[1];
  const float* u  = (const float*)d_in[2];
  const float* v  = (const float*)d_in[3];
  const float* mp = (const float*)d_in[4];
  const float* bp = (const float*)d_in[5];
  float* out = (float*)d_out;

  int N = in_sizes[1];                       // number of points
  int M = in_sizes[4] / (TEXELS * 9);        // number of materials

  int total_texels = M * TEXELS;
  size_t need = (size_t)total_texels * 16;   // 16 B per texel
  if (ws_size >= need) {
    repack_q10m_kernel<<<(total_texels + 255) / 256, 256, 0, stream>>>(
        mp, bp, (uint4*)d_ws, total_texels);
    int pairs = (N + 1) / 2;
    interp_q10m_kernel<<<(pairs + 255) / 256, 256, 0, stream>>>(
        x, m, u, v, (const uint4*)d_ws, out, N);
  } else {
    interp_direct_kernel<<<(N + 255) / 256, 256, 0, stream>>>(
        x, m, u, v, mp, bp, out, N);
  }
}

// Round 5
// 246.025 us; speedup vs baseline: 1.0631x; 1.0631x over previous
//
#include <hip/hip_runtime.h>
#include <math.h>

#define U_DIM 400
#define V_DIM 400
#define TEXELS (U_DIM * V_DIM)
#define VHALF (V_DIM / 2)

// ---------------- q10 packed path, 2x2 tiled ----------------
// Per-texel record: 16 B = 128 bits:
//   bits [10k, 10k+10) for k=0..11 : q_k = round(v_k * 2^(9-e)) + 512  (10-bit)
//   bits [120,128)                 : Eb = e + 127 (biased exponent of max|v|)
// Dequant: v_k = (q_k - 512) * 2^(e-9) (power-of-2 scale, exact in fp32).
//
// Layout: records stored in 2x2 texel blocks, 64 B aligned:
//   R(i,j) = ((i>>1)*VHALF + (j>>1))*4 + (i&1)*2 + (j&1)
// A bilinear query's 4 corners span on average 2.25 blocks x 64 B = 144 B of
// cache footprint (measured: FETCH 388->344 MB vs row-major).
//
// Interp is ONE point per thread: the 3x4B nt-store pattern (12 B/lane
// stride) measures exactly output-sized HBM writes; wider per-thread strides
// doubled WRITE_SIZE via partial-line nt writes (round-4 post-mortem).

__device__ __forceinline__ unsigned morton_idx(int i, int j) {
  return (unsigned)(((i >> 1) * VHALF + (j >> 1)) << 2) + ((i & 1) << 1) + (j & 1);
}

__global__ __launch_bounds__(256) void repack_q10m_kernel(
    const float* __restrict__ mp, const float* __restrict__ bp,
    uint4* __restrict__ packed, int total_texels) {
  int t = blockIdx.x * blockDim.x + threadIdx.x;
  if (t >= total_texels) return;
  float vals[12];
  const float* pm = mp + (size_t)t * 9;
  const float* pb = bp + (size_t)t * 3;
#pragma unroll
  for (int k = 0; k < 9; ++k) vals[k] = __builtin_nontemporal_load(pm + k);
#pragma unroll
  for (int k = 0; k < 3; ++k) vals[9 + k] = __builtin_nontemporal_load(pb + k);

  float mx = 0.0f;
#pragma unroll
  for (int k = 0; k < 12; ++k) mx = fmaxf(mx, fabsf(vals[k]));
  int e;
  (void)frexpf(mx, &e);  // mx = f * 2^e, f in [0.5,1); mx==0 -> e=0
  int Eb = e + 127;
  if (Eb < 10) Eb = 10;
  if (Eb > 255) Eb = 255;
  float inv = __uint_as_float((unsigned)((9 - (Eb - 127) + 127) << 23));  // 2^(9-e)

  unsigned d[4] = {0u, 0u, 0u, 0u};
#pragma unroll
  for (int k = 0; k < 12; ++k) {
    float qf = rintf(vals[k] * inv);
    qf = fminf(fmaxf(qf, -512.0f), 511.0f);
    unsigned q = (unsigned)((int)qf + 512);
    int bit = 10 * k;
    d[bit >> 5] |= q << (bit & 31);
    if ((bit & 31) + 10 > 32) d[(bit >> 5) + 1] |= q >> (32 - (bit & 31));
  }
  d[3] |= (unsigned)Eb << 24;

  int mi = t / TEXELS;
  int r  = t - mi * TEXELS;
  int i  = r / V_DIM;
  int j  = r - i * V_DIM;
  unsigned R = (unsigned)mi * (unsigned)TEXELS + morton_idx(i, j);
  packed[R] = make_uint4(d[0], d[1], d[2], d[3]);
}

__device__ __forceinline__ void accum_q10(uint4 r, float wc, float* acc,
                                          float& wsum) {
  unsigned d0 = r.x, d1 = r.y, d2 = r.z, d3 = r.w;
  float s = __uint_as_float(((d3 >> 24) - 9u) << 23);  // 2^(e-9), exact
  float ws = wc * s;
  wsum += ws;
  unsigned q[12];
  q[0]  = d0 & 1023u;
  q[1]  = (d0 >> 10) & 1023u;
  q[2]  = (d0 >> 20) & 1023u;
  q[3]  = ((d0 >> 30) | (d1 << 2)) & 1023u;
  q[4]  = (d1 >> 8) & 1023u;
  q[5]  = (d1 >> 18) & 1023u;
  q[6]  = ((d1 >> 28) | (d2 << 4)) & 1023u;
  q[7]  = (d2 >> 6) & 1023u;
  q[8]  = (d2 >> 16) & 1023u;
  q[9]  = ((d2 >> 26) | (d3 << 6)) & 1023u;
  q[10] = (d3 >> 4) & 1023u;
  q[11] = (d3 >> 14) & 1023u;
#pragma unroll
  for (int k = 0; k < 12; ++k)
    acc[k] = fmaf(ws, (float)q[k], acc[k]);
}

__global__ __launch_bounds__(256) void interp_q10m_kernel(
    const float* __restrict__ x, const int* __restrict__ mat,
    const float* __restrict__ u, const float* __restrict__ v,
    const uint4* __restrict__ packed, float* __restrict__ out, int N) {
  int n = blockIdx.x * blockDim.x + threadIdx.x;
  if (n >= N) return;

  // Streams read once: non-temporal so they don't evict table lines in L2.
  float un = __builtin_nontemporal_load(u + n);
  float vn = __builtin_nontemporal_load(v + n);
  int   mn = __builtin_nontemporal_load(mat + n);

  float iu = un * (float)U_DIM; if (iu >= (float)U_DIM) iu = (float)(U_DIM - 1);
  float jv = vn * (float)V_DIM; if (jv >= (float)V_DIM) jv = (float)(V_DIM - 1);
  float i1f = floorf(iu), j1f = floorf(jv);
  int i1 = (int)i1f, j1 = (int)j1f;
  int i2 = i1 + 1; if (i2 == U_DIM) i2 = 0;
  int j2 = j1 + 1; if (j2 == V_DIM) j2 = 0;
  float ir = iu - i1f, jr = jv - j1f;

  float w00 = (1.0f - ir) * (1.0f - jr);  // (i1,j1)
  float w10 = ir * (1.0f - jr);           // (i2,j1)
  float w01 = (1.0f - ir) * jr;           // (i1,j2)
  float w11 = ir * jr;                    // (i2,j2)

  const uint4* base = packed + (size_t)mn * (size_t)TEXELS;
  // Issue all 4 gather loads up front for max MLP.
  uint4 r00 = base[morton_idx(i1, j1)];
  uint4 r10 = base[morton_idx(i2, j1)];
  uint4 r01 = base[morton_idx(i1, j2)];
  uint4 r11 = base[morton_idx(i2, j2)];

  float x0 = __builtin_nontemporal_load(x + 3 * (size_t)n + 0);
  float x1 = __builtin_nontemporal_load(x + 3 * (size_t)n + 1);
  float x2 = __builtin_nontemporal_load(x + 3 * (size_t)n + 2);

  float acc[12];
#pragma unroll
  for (int c = 0; c < 12; ++c) acc[c] = 0.0f;
  float wsum = 0.0f;

  accum_q10(r00, w00, acc, wsum);
  accum_q10(r10, w10, acc, wsum);
  accum_q10(r01, w01, acc, wsum);
  accum_q10(r11, w11, acc, wsum);

  // True value of each coeff is acc[k] - 512*wsum; fold into one correction:
  //   o_j = raw_j - 512*wsum*(x0+x1+x2+1)
  float cc = (512.0f * wsum) * (x0 + x1 + x2 + 1.0f);

  float o0 = fmaf(x0, acc[0], fmaf(x1, acc[3], fmaf(x2, acc[6], acc[9])))  - cc;
  float o1 = fmaf(x0, acc[1], fmaf(x1, acc[4], fmaf(x2, acc[7], acc[10]))) - cc;
  float o2 = fmaf(x0, acc[2], fmaf(x1, acc[5], fmaf(x2, acc[8], acc[11]))) - cc;
  __builtin_nontemporal_store(o0, out + 3 * (size_t)n + 0);
  __builtin_nontemporal_store(o1, out + 3 * (size_t)n + 1);
  __builtin_nontemporal_store(o2, out + 3 * (size_t)n + 2);
}

// ---------------- fp32 direct fallback (ws too small) ----------------
__global__ __launch_bounds__(256) void interp_direct_kernel(
    const float* __restrict__ x, const int* __restrict__ mat,
    const float* __restrict__ u, const float* __restrict__ v,
    const float* __restrict__ mp, const float* __restrict__ bp,
    float* __restrict__ out, int N) {
  int n = blockIdx.x * blockDim.x + threadIdx.x;
  if (n >= N) return;

  float iu = u[n] * (float)U_DIM; if (iu >= (float)U_DIM) iu = (float)(U_DIM - 1);
  float jv = v[n] * (float)V_DIM; if (jv >= (float)V_DIM) jv = (float)(V_DIM - 1);
  float i1f = floorf(iu), j1f = floorf(jv);
  int i1 = (int)i1f, j1 = (int)j1f;
  int i2 = i1 + 1; if (i2 == U_DIM) i2 = 0;
  int j2 = j1 + 1; if (j2 == V_DIM) j2 = 0;
  float ir = iu - i1f, jr = jv - j1f;

  float w[4];
  w[0] = (1.0f - ir) * (1.0f - jr);
  w[1] = ir * (1.0f - jr);
  w[2] = (1.0f - ir) * jr;
  w[3] = ir * jr;
  int t[4];
  t[0] = i1 * V_DIM + j1;
  t[1] = i2 * V_DIM + j1;
  t[2] = i1 * V_DIM + j2;
  t[3] = i2 * V_DIM + j2;

  size_t mb = (size_t)mat[n] * TEXELS;
  float acc[12];
#pragma unroll
  for (int c = 0; c < 12; ++c) acc[c] = 0.0f;
#pragma unroll
  for (int c = 0; c < 4; ++c) {
    const float* pm = mp + (mb + t[c]) * 9;
    const float* pb = bp + (mb + t[c]) * 3;
    float wc = w[c];
#pragma unroll
    for (int k = 0; k < 9; ++k) acc[k] = fmaf(wc, pm[k], acc[k]);
#pragma unroll
    for (int k = 0; k < 3; ++k) acc[9 + k] = fmaf(wc, pb[k], acc[9 + k]);
  }

  float x0 = x[3 * n + 0];
  float x1 = x[3 * n + 1];
  float x2 = x[3 * n + 2];
  float o0 = fmaf(x0, acc[0], fmaf(x1, acc[3], fmaf(x2, acc[6], acc[9])));
  float o1 = fmaf(x0, acc[1], fmaf(x1, acc[4], fmaf(x2, acc[7], acc[10])));
  float o2 = fmaf(x0, acc[2], fmaf(x1, acc[5], fmaf(x2, acc[8], acc[11])));
  out[3 * n + 0] = o0;
  out[3 * n + 1] = o1;
  out[3 * n + 2] = o2;
}

extern "C" void kernel_launch(void* const* d_in, const int* in_sizes, int n_in,
                              void* d_out, int out_size, void* d_ws, size_t ws_size,
                              hipStream_t stream) {
  const float* x  = (const float*)d_in[0];
  const int*   m  = (const int*)d_in[1];
  const float* u  = (const float*)d_in[2];
  const float* v  = (const float*)d_in[3];
  const float* mp = (const float*)d_in[4];
  const float* bp = (const float*)d_in[5];
  float* out = (float*)d_out;

  int N = in_sizes[1];                       // number of points
  int M = in_sizes[4] / (TEXELS * 9);        // number of materials

  int total_texels = M * TEXELS;
  size_t need = (size_t)total_texels * 16;   // 16 B per texel
  if (ws_size >= need) {
    repack_q10m_kernel<<<(total_texels + 255) / 256, 256, 0, stream>>>(
        mp, bp, (uint4*)d_ws, total_texels);
    interp_q10m_kernel<<<(N + 255) / 256, 256, 0, stream>>>(
        x, m, u, v, (const uint4*)d_ws, out, N);
  } else {
    interp_direct_kernel<<<(N + 255) / 256, 256, 0, stream>>>(
        x, m, u, v, mp, bp, out, N);
  }
}